// Round 9
// baseline (503.739 us; speedup 1.0000x reference)
//
#include <hip/hip_runtime.h>
#include <math.h>

// PhaseRefinement fused kernel, v9: R2 traffic structure (x LDS-staged once
// per block) + coarse double-buffered groups + R5/R8 tail.
// Ledger: R5 (barrier-free, 415us) is L2-bound: each x row read 8x from L2
// (7.4 GB total, ~230us floor). LDS staging cuts L2 to 3.7 GB. R2 (staged,
// per-chunk barrier) convoyed on 17 vmcnt(0) drains; R6 (counted vmcnt,
// runtime ring) hit compiler conservative waits; R7 (4-chunk groups,
// unrolled) spilled (live W loads) and 67KB LDS broke 2-block residency
// (~128KB co-residency limit). v9 threads the needle:
//  - groups of 4 chunks (1024 cols), double-buffered: 5 barriers/block,
//    group compute (~1200cyc) covers the stage drain
//  - group loop PEELED -> compile-time LDS buffer indices (alias-clean)
//  - inner sub-chunk loop '#pragma unroll 1' -> no load hoisting, live set
//    ~105 VGPR < 128, no spill
//  - LDS = exactly 64 KB: tail arrays (dots/stats/scale) UNION'd into the
//    x buffer (dead after main loop) -> 2 blocks/CU co-resident
//
// out = x + LN(c*x)*gamma + beta; LN(c*x) collapses to
//   normed = gamma*(alpha*x - alpha*mu) + beta,
//   alpha = c*rsqrt(c^2*var + 1e-5), mu/var = plain row stats of x.

constexpr int Dh     = 4096;
constexpr int Ph     = 16;
constexpr int NPL    = 32;
constexpr int CHUNK  = 256;            // 64 lanes * 4 floats
constexpr int GCHUNK = 4;              // chunks per group (1024 cols)
constexpr int NGRP   = Dh / (CHUNK * GCHUNK);  // 4
constexpr int RPB    = 8;              // rows per block
constexpr int NW     = 8;              // waves per block
constexpr int PPW    = NPL / NW;       // 4 planes per wave
constexpr int BLOCK  = 64 * NW;        // 512

__device__ __forceinline__ void stage_chunk(const float* src, float* ldsdst) {
    __builtin_amdgcn_global_load_lds(
        (const __attribute__((address_space(1))) void*)src,
        (__attribute__((address_space(3))) void*)ldsdst, 16, 0, 0);
}

__global__ __launch_bounds__(BLOCK, 2)
void phase_fused(const float* __restrict__ x,
                 const float* __restrict__ Wr,
                 const float* __restrict__ br,
                 const float* __restrict__ Wo,
                 const float* __restrict__ bo,
                 const float* __restrict__ gamma,
                 const float* __restrict__ beta,
                 float* __restrict__ out)
{
    // 2 x 32 KB x-buffers; tail arrays reuse buffer 0 after the main loop.
    __shared__ float x_lds[2][GCHUNK][RPB][CHUNK];      // 65536 B total
    float* const dots_f  = &x_lds[0][0][0][0];          // [RPB*NPL] = 256
    float* const stats_f = dots_f + RPB * NPL;          // sx[8], sxx[8]
    float* const scale_f = stats_f + 16;                // alpha[8], am[8]

    const int t    = threadIdx.x;
    const int wv   = t >> 6;
    const int lane = t & 63;
    const size_t rowbase = (size_t)blockIdx.x * RPB;

    // Wave wv's 4 W rows (planes wv*4..+3; 0..15 refine, 16..31 out), lane-folded.
    const float* wrow[PPW];
#pragma unroll
    for (int p = 0; p < PPW; ++p) {
        const int q = wv * PPW + p;
        wrow[p] = ((q < Ph) ? (Wr + (size_t)q * Dh) : (Wo + (size_t)(q - Ph) * Dh))
                  + lane * 4;
    }
    // Wave wv stages row wv; global src per-lane, LDS dst wave-uniform linear.
    const float* xsrc = x + (rowbase + wv) * (size_t)Dh + lane * 4;

    float acc[RPB][PPW];
#pragma unroll
    for (int r = 0; r < RPB; ++r)
#pragma unroll
        for (int p = 0; p < PPW; ++p) acc[r][p] = 0.f;
    float sx = 0.f, sxx = 0.f;

    // Stage one 1024-col group (4 chunks) of this wave's row into buf.
    auto stage_group = [&](int g, int buf) {
#pragma unroll
        for (int k = 0; k < GCHUNK; ++k)
            stage_chunk(xsrc + (size_t)(g * GCHUNK + k) * CHUNK,
                        &x_lds[buf][k][wv][0]);
    };

    // Compute one group from buf. Inner loop unroll 1: keeps live set at
    // ~13 loads (no cross-iteration hoisting -> no spill, R7's failure).
    auto compute_group = [&](int g, int buf) {
#pragma unroll 1
        for (int k = 0; k < GCHUNK; ++k) {
            const int off = (g * GCHUNK + k) * CHUNK;
            float4 w4[PPW];
#pragma unroll
            for (int p = 0; p < PPW; ++p)
                w4[p] = *(const float4*)(wrow[p] + off);
            float4 x4[RPB];
#pragma unroll
            for (int r = 0; r < RPB; ++r)
                x4[r] = *(const float4*)(&x_lds[buf][k][r][lane * 4]);
            float4 xs = *(const float4*)(&x_lds[buf][k][wv][lane * 4]);

            sx  += xs.x + xs.y + xs.z + xs.w;
            sxx += xs.x*xs.x + xs.y*xs.y + xs.z*xs.z + xs.w*xs.w;

#pragma unroll
            for (int r = 0; r < RPB; ++r)
#pragma unroll
                for (int p = 0; p < PPW; ++p)
                    acc[r][p] += x4[r].x*w4[p].x + x4[r].y*w4[p].y
                               + x4[r].z*w4[p].z + x4[r].w*w4[p].w;
        }
    };

    // Peeled pipeline: compile-time buffer indices everywhere.
    stage_group(0, 0);
    __syncthreads();                       // stage(0) landed
    stage_group(1, 1); compute_group(0, 0);
    __syncthreads();                       // stage(1) landed; buf0 free
    stage_group(2, 0); compute_group(1, 1);
    __syncthreads();                       // stage(2) landed; buf1 free
    stage_group(3, 1); compute_group(2, 0);
    __syncthreads();                       // stage(3) landed; buf0 now dead
    compute_group(3, 1);

    // Butterfly-reduce accumulators across the 64 lanes.
    // dots/stats land in the (dead) buf0 region; distinct addresses per wave.
#pragma unroll
    for (int r = 0; r < RPB; ++r)
#pragma unroll
        for (int p = 0; p < PPW; ++p) {
            float v = acc[r][p];
#pragma unroll
            for (int m = 1; m < 64; m <<= 1) v += __shfl_xor(v, m, 64);
            if (lane == 0) dots_f[r * NPL + wv * PPW + p] = v;
        }
#pragma unroll
    for (int m = 1; m < 64; m <<= 1) {
        sx  += __shfl_xor(sx, m, 64);
        sxx += __shfl_xor(sxx, m, 64);
    }
    if (lane == 0) { stats_f[wv] = sx; stats_f[8 + wv] = sxx; }
    __syncthreads();

    // Scalar phase, parallel over (row, plane): 128 threads, 16-lane reduce.
    if (t < RPB * Ph) {
        const int r = t >> 4, p = t & 15;
        float d1 = dots_f[r * NPL + p]      + br[p];
        float d2 = dots_f[r * NPL + Ph + p] + bo[p];
        float cd = cosf((tanhf(d1) - tanhf(d2)) * 3.14159265358979323846f);
#pragma unroll
        for (int m = 1; m < 16; m <<= 1) cd += __shfl_xor(cd, m, 16);
        if (p == 0) {
            float s    = cd;
            float gain = log1pf(expf(s * (1.f / Ph) + 0.5f));  // softplus
            float cm   = s * gain * (1.f / Ph);
            float mu   = stats_f[r] * (1.f / Dh);
            float var  = stats_f[8 + r] * (1.f / Dh) - mu * mu;
            var = fmaxf(var, 0.f);
            float rstd  = rsqrtf(cm * cm * var + 1e-5f);
            float alpha = cm * rstd;
            scale_f[r]     = alpha;
            scale_f[8 + r] = alpha * mu;
        }
    }
    __syncthreads();

    // Phase B, column-sliced: wave wv owns cols [wv*512, wv*512+512);
    // gamma/beta loaded ONCE per wave, reused across all 8 rows. x re-read
    // is L2-hot (FETCH_SIZE ~= x-once at HBM every round).
    {
        const int col0 = wv * 512 + lane * 4;
        const float4 g4a = *(const float4*)(gamma + col0);
        const float4 g4b = *(const float4*)(gamma + col0 + 256);
        const float4 b4a = *(const float4*)(beta  + col0);
        const float4 b4b = *(const float4*)(beta  + col0 + 256);
#pragma unroll
        for (int r = 0; r < RPB; ++r) {
            const float alpha = scale_f[r];
            const float am    = scale_f[8 + r];
            const float* xr  = x   + (rowbase + r) * (size_t)Dh;
            float*       orw = out + (rowbase + r) * (size_t)Dh;
            float4 xa = *(const float4*)(xr + col0);
            float4 xb = *(const float4*)(xr + col0 + 256);
            float4 oa, ob;
            oa.x = xa.x + g4a.x * (alpha * xa.x - am) + b4a.x;
            oa.y = xa.y + g4a.y * (alpha * xa.y - am) + b4a.y;
            oa.z = xa.z + g4a.z * (alpha * xa.z - am) + b4a.z;
            oa.w = xa.w + g4a.w * (alpha * xa.w - am) + b4a.w;
            ob.x = xb.x + g4b.x * (alpha * xb.x - am) + b4b.x;
            ob.y = xb.y + g4b.y * (alpha * xb.y - am) + b4b.y;
            ob.z = xb.z + g4b.z * (alpha * xb.z - am) + b4b.z;
            ob.w = xb.w + g4b.w * (alpha * xb.w - am) + b4b.w;
            *(float4*)(orw + col0)       = oa;
            *(float4*)(orw + col0 + 256) = ob;
        }
    }
}

extern "C" void kernel_launch(void* const* d_in, const int* in_sizes, int n_in,
                              void* d_out, int out_size, void* d_ws, size_t ws_size,
                              hipStream_t stream)
{
    const float* x     = (const float*)d_in[0];
    const float* Wr    = (const float*)d_in[1];
    const float* br    = (const float*)d_in[2];
    const float* Wo    = (const float*)d_in[3];
    const float* bo    = (const float*)d_in[4];
    const float* gamma = (const float*)d_in[5];
    const float* beta  = (const float*)d_in[6];
    float* out = (float*)d_out;

    const int B = in_sizes[0] / Dh;       // 32768
    dim3 grid(B / RPB);                   // 4096 blocks
    phase_fused<<<grid, BLOCK, 0, stream>>>(x, Wr, br, Wo, bo, gamma, beta, out);
}

// Round 11
// 385.986 us; speedup vs baseline: 1.3051x; 1.3051x over previous
//
#include <hip/hip_runtime.h>
#include <math.h>

// PhaseRefinement fused kernel, v11 = v10 with the W-load addressing fixed.
// v10's compile failure was exactly the 4 W loads: their bases depend on
// wv = threadIdx>>6, which the compiler cannot prove wave-uniform, so the
// "s" constraint is illegal for them. x bases are block-uniform -> saddr
// form is fine (those 8 loads compiled in v10). Fix: x loads keep saddr
// (SGPR base + one shared voffset VGPR); W loads use flat-global form
// (64-bit VGPR address pair), pointers advanced in C per chunk.
//
// Why forced-asm batching: 5 rounds of evidence (v5..v9) that the compiler
// never keeps >3-4 of the 12 independent per-chunk loads in flight
// (VGPR 60-68 every time), so each 256-col chunk pays 3-4 serialized
// latencies. Ordered volatile asm + one s_waitcnt vmcnt(0) +
// sched_barrier(0) makes MLP=12 per wave by construction.
//
// out = x + LN(c*x)*gamma + beta; LN(c*x) collapses to
//   normed = gamma*(alpha*x - alpha*mu) + beta,
//   alpha = c*rsqrt(c^2*var + 1e-5), mu/var = plain row stats of x.

constexpr int Dh     = 4096;
constexpr int Ph     = 16;
constexpr int NPL    = 32;          // 2*P dots per row
constexpr int CHUNK  = 256;         // 64 lanes * 4 floats
constexpr int NCHUNK = Dh / CHUNK;  // 16
constexpr int RPB    = 8;           // rows per block
constexpr int NW     = 8;           // waves per block
constexpr int PPW    = NPL / NW;    // 4 planes per wave
constexpr int BLOCK  = 64 * NW;     // 512

// saddr form: wave-uniform (block-uniform) base in SGPR pair + shared
// 32-bit per-lane byte offset VGPR. Volatile => program-ordered.
__device__ __forceinline__ float4 gload_s(const float* sbase, int voff) {
    float4 v;
    asm volatile("global_load_dwordx4 %0, %1, %2"
                 : "=v"(v) : "v"(voff), "s"(sbase));
    return v;
}

// flat-global form: full 64-bit per-lane address in a VGPR pair.
__device__ __forceinline__ float4 gload_v(const float* addr) {
    float4 v;
    asm volatile("global_load_dwordx4 %0, %1, off"
                 : "=v"(v) : "v"(addr));
    return v;
}

__global__ __launch_bounds__(BLOCK, 2)
void phase_fused(const float* __restrict__ x,
                 const float* __restrict__ Wr,
                 const float* __restrict__ br,
                 const float* __restrict__ Wo,
                 const float* __restrict__ bo,
                 const float* __restrict__ gamma,
                 const float* __restrict__ beta,
                 float* __restrict__ out)
{
    __shared__ float dots_lds[RPB][NPL];
    __shared__ float stats_lds[RPB][2];
    __shared__ float scale_lds[RPB][2];

    const int t    = threadIdx.x;
    const int wv   = t >> 6;
    const int lane = t & 63;
    const size_t rowbase = (size_t)blockIdx.x * RPB;

    // Block-uniform x bases (no lane offset -> SGPR pairs for saddr form).
    const float* xbase[RPB];
#pragma unroll
    for (int r = 0; r < RPB; ++r)
        xbase[r] = x + (rowbase + r) * (size_t)Dh;

    // Per-wave W pointers (lane offset folded in; advanced per chunk).
    const float* wptr[PPW];
#pragma unroll
    for (int p = 0; p < PPW; ++p) {
        const int q = wv * PPW + p;
        wptr[p] = ((q < Ph) ? (Wr + (size_t)q * Dh) : (Wo + (size_t)(q - Ph) * Dh))
                  + lane * 4;
    }

    float acc[RPB][PPW];
#pragma unroll
    for (int r = 0; r < RPB; ++r)
#pragma unroll
        for (int p = 0; p < PPW; ++p) acc[r][p] = 0.f;
    float sx = 0.f, sxx = 0.f;

    int voff = lane * 16;              // per-lane byte offset, +1024/chunk
#pragma unroll 1
    for (int c = 0; c < NCHUNK; ++c) {
        // 12 ordered asm loads: all issue before the waitcnt, results
        // forced live -> 12 vmem in flight per wave.
        float4 x4[RPB];
#pragma unroll
        for (int r = 0; r < RPB; ++r)
            x4[r] = gload_s(xbase[r], voff);
        float4 w4[PPW];
#pragma unroll
        for (int p = 0; p < PPW; ++p)
            w4[p] = gload_v(wptr[p]);

        asm volatile("s_waitcnt vmcnt(0)" ::: "memory");
        __builtin_amdgcn_sched_barrier(0);   // rule #18: no consumer hoisting

#pragma unroll
        for (int r = 0; r < RPB; ++r) {
            if (r == wv) {   // wave-uniform; static indices
                sx  += x4[r].x + x4[r].y + x4[r].z + x4[r].w;
                sxx += x4[r].x*x4[r].x + x4[r].y*x4[r].y
                     + x4[r].z*x4[r].z + x4[r].w*x4[r].w;
            }
#pragma unroll
            for (int p = 0; p < PPW; ++p)
                acc[r][p] += x4[r].x*w4[p].x + x4[r].y*w4[p].y
                           + x4[r].z*w4[p].z + x4[r].w*w4[p].w;
        }
        voff += CHUNK * 4;
#pragma unroll
        for (int p = 0; p < PPW; ++p) wptr[p] += CHUNK;
    }

    // Butterfly-reduce accumulators across the 64 lanes.
#pragma unroll
    for (int r = 0; r < RPB; ++r)
#pragma unroll
        for (int p = 0; p < PPW; ++p) {
            float v = acc[r][p];
#pragma unroll
            for (int m = 1; m < 64; m <<= 1) v += __shfl_xor(v, m, 64);
            if (lane == 0) dots_lds[r][wv * PPW + p] = v;
        }
#pragma unroll
    for (int m = 1; m < 64; m <<= 1) {
        sx  += __shfl_xor(sx, m, 64);
        sxx += __shfl_xor(sxx, m, 64);
    }
    if (lane == 0) { stats_lds[wv][0] = sx; stats_lds[wv][1] = sxx; }
    __syncthreads();

    // Scalar phase, parallel over (row, plane): 128 threads, 16-lane reduce.
    if (t < RPB * Ph) {
        const int r = t >> 4, p = t & 15;
        float d1 = dots_lds[r][p]      + br[p];
        float d2 = dots_lds[r][Ph + p] + bo[p];
        float cd = cosf((tanhf(d1) - tanhf(d2)) * 3.14159265358979323846f);
#pragma unroll
        for (int m = 1; m < 16; m <<= 1) cd += __shfl_xor(cd, m, 16);
        if (p == 0) {
            float s    = cd;
            float gain = log1pf(expf(s * (1.f / Ph) + 0.5f));  // softplus
            float cm   = s * gain * (1.f / Ph);
            float mu   = stats_lds[r][0] * (1.f / Dh);
            float var  = stats_lds[r][1] * (1.f / Dh) - mu * mu;
            var = fmaxf(var, 0.f);
            float rstd  = rsqrtf(cm * cm * var + 1e-5f);
            float alpha = cm * rstd;
            scale_lds[r][0] = alpha;
            scale_lds[r][1] = alpha * mu;
        }
    }
    __syncthreads();

    // Phase B, column-sliced: wave wv owns cols [wv*512, wv*512+512);
    // gamma/beta loaded ONCE per wave, reused across all 8 rows. x re-read
    // is L2-hot (FETCH_SIZE ~= x-once at HBM every round).
    {
        const int col0 = wv * 512 + lane * 4;
        const float4 g4a = *(const float4*)(gamma + col0);
        const float4 g4b = *(const float4*)(gamma + col0 + 256);
        const float4 b4a = *(const float4*)(beta  + col0);
        const float4 b4b = *(const float4*)(beta  + col0 + 256);
#pragma unroll
        for (int r = 0; r < RPB; ++r) {
            const float alpha = scale_lds[r][0];
            const float am    = scale_lds[r][1];
            const float* xr  = x   + (rowbase + r) * (size_t)Dh;
            float*       orw = out + (rowbase + r) * (size_t)Dh;
            float4 xa = *(const float4*)(xr + col0);
            float4 xb = *(const float4*)(xr + col0 + 256);
            float4 oa, ob;
            oa.x = xa.x + g4a.x * (alpha * xa.x - am) + b4a.x;
            oa.y = xa.y + g4a.y * (alpha * xa.y - am) + b4a.y;
            oa.z = xa.z + g4a.z * (alpha * xa.z - am) + b4a.z;
            oa.w = xa.w + g4a.w * (alpha * xa.w - am) + b4a.w;
            ob.x = xb.x + g4b.x * (alpha * xb.x - am) + b4b.x;
            ob.y = xb.y + g4b.y * (alpha * xb.y - am) + b4b.y;
            ob.z = xb.z + g4b.z * (alpha * xb.z - am) + b4b.z;
            ob.w = xb.w + g4b.w * (alpha * xb.w - am) + b4b.w;
            *(float4*)(orw + col0)       = oa;
            *(float4*)(orw + col0 + 256) = ob;
        }
    }
}

extern "C" void kernel_launch(void* const* d_in, const int* in_sizes, int n_in,
                              void* d_out, int out_size, void* d_ws, size_t ws_size,
                              hipStream_t stream)
{
    const float* x     = (const float*)d_in[0];
    const float* Wr    = (const float*)d_in[1];
    const float* br    = (const float*)d_in[2];
    const float* Wo    = (const float*)d_in[3];
    const float* bo    = (const float*)d_in[4];
    const float* gamma = (const float*)d_in[5];
    const float* beta  = (const float*)d_in[6];
    float* out = (float*)d_out;

    const int B = in_sizes[0] / Dh;       // 32768
    dim3 grid(B / RPB);                   // 4096 blocks
    phase_fused<<<grid, BLOCK, 0, stream>>>(x, Wr, br, Wo, bo, gamma, beta, out);
}